// Round 1
// baseline (503.921 us; speedup 1.0000x reference)
//
#include <hip/hip_runtime.h>
#include <math.h>

#define NUM_NODES 94
#define NP 96            // nodes padded to 96 (zero weights for 94,95)
#define SEQ_LEN 784
#define OUT_CLASSES 10
#define B_BLK 2          // batch elements per block
#define THREADS (NP * B_BLK)   // 192 threads = 3 waves

#define ALPHA 0.5f
#define TWO_GAMMA 0.2f
#define OM2 0.0503551324598949f          // (2*pi/28)^2
#define INV_SQRT_N 0.103142124625879f    // 1/sqrt(94)

__global__ __launch_bounds__(THREADS) void horn_kernel(
    const float* __restrict__ input,   // (1024, 784)
    const float* __restrict__ w_ih,    // (94, 1)
    const float* __restrict__ b_ih,    // (94)
    const float* __restrict__ w_hh,    // (94, 94)
    const float* __restrict__ b_hh,    // (94)
    const float* __restrict__ w_ro,    // (10, 94)
    const float* __restrict__ b_ro,    // (10)
    float* __restrict__ out)           // (1024, 10)
{
    __shared__ float ylds[2][B_BLK][NP];     // double-buffered y state
    __shared__ float slds[B_BLK][SEQ_LEN];   // prefetched input rows

    const int tid = threadIdx.x;
    const int n = tid % NP;          // node index (padded)
    const int b = tid / NP;          // local batch index
    const int b0 = blockIdx.x * B_BLK;

    // Prefetch this block's input rows into LDS (coalesced).
    for (int idx = tid; idx < B_BLK * SEQ_LEN; idx += THREADS) {
        int bb = idx / SEQ_LEN;
        int t  = idx % SEQ_LEN;
        slds[bb][t] = input[(size_t)(b0 + bb) * SEQ_LEN + t];
    }

    // Init y buffers to zero.
    ylds[0][b][n] = 0.0f;
    ylds[1][b][n] = 0.0f;

    const bool active = (n < NUM_NODES);

    // Load w_hh row n into registers (zero for padding lanes).
    float w[NP];
    #pragma unroll
    for (int j = 0; j < NP; j++) {
        w[j] = (active && j < NUM_NODES) ? w_hh[n * NUM_NODES + j] : 0.0f;
    }
    const float wih_n = active ? w_ih[n] : 0.0f;
    const float bih_n = active ? b_ih[n] : 0.0f;
    const float bhh_n = active ? b_hh[n] : 0.0f;

    float x = 0.0f, y = 0.0f;

    __syncthreads();

    int p = 0;
    for (int t = 0; t < SEQ_LEN; t++) {
        // I_rec[n] = sum_j w_hh[n][j] * y[j]  — y read as broadcast float4s.
        float acc = 0.0f;
        const float4* yv = (const float4*)&ylds[p][b][0];
        #pragma unroll
        for (int j4 = 0; j4 < NP / 4; j4++) {
            float4 y4 = yv[j4];
            acc += w[4 * j4 + 0] * y4.x;
            acc += w[4 * j4 + 1] * y4.y;
            acc += w[4 * j4 + 2] * y4.z;
            acc += w[4 * j4 + 3] * y4.w;
        }

        float s_t = slds[b][t];
        float A = (s_t * wih_n + bih_n + acc + bhh_n) * INV_SQRT_N;

        // tanh(A) = 1 - 2/(exp(2A)+1); exp(inf) path is NaN-free.
        float e  = __expf(2.0f * A);
        float th = 1.0f - __fdividef(2.0f, e + 1.0f);

        float accel = ALPHA * th - TWO_GAMMA * y - OM2 * x;
        x += y;          // H = 1: x_new = x + y (old y)
        y += accel;      // y_new = y + accel

        ylds[p ^ 1][b][n] = y;   // padding lanes stay 0 (their accel == 0)
        __syncthreads();
        p ^= 1;
    }

    // Epilogue: out[b][c] = sum_n x[b][n] * w_ro[c][n] + b_ro[c]
    ylds[0][b][n] = active ? x : 0.0f;
    __syncthreads();

    if (tid < B_BLK * OUT_CLASSES) {
        int bb = tid / OUT_CLASSES;
        int c  = tid % OUT_CLASSES;
        float s = b_ro[c];
        #pragma unroll 2
        for (int j = 0; j < NUM_NODES; j++) {
            s += ylds[0][bb][j] * w_ro[c * NUM_NODES + j];
        }
        out[(size_t)(b0 + bb) * OUT_CLASSES + c] = s;
    }
}

extern "C" void kernel_launch(void* const* d_in, const int* in_sizes, int n_in,
                              void* d_out, int out_size, void* d_ws, size_t ws_size,
                              hipStream_t stream) {
    const float* input = (const float*)d_in[0];
    const float* w_ih  = (const float*)d_in[1];
    const float* b_ih  = (const float*)d_in[2];
    const float* w_hh  = (const float*)d_in[3];
    const float* b_hh  = (const float*)d_in[4];
    const float* w_ro  = (const float*)d_in[5];
    const float* b_ro  = (const float*)d_in[6];
    float* out = (float*)d_out;

    const int batch = in_sizes[0] / SEQ_LEN;   // 1024
    dim3 grid(batch / B_BLK);                  // 512 blocks
    dim3 block(THREADS);                       // 192 threads

    hipLaunchKernelGGL(horn_kernel, grid, block, 0, stream,
                       input, w_ih, b_ih, w_hh, b_hh, w_ro, b_ro, out);
}